// Round 1
// baseline (7317.603 us; speedup 1.0000x reference)
//
#include <hip/hip_runtime.h>
#include <hip/hip_bf16.h>
#include <hip/hip_cooperative_groups.h>
#include <cstdint>
#include <cstddef>

namespace cg = cooperative_groups;

typedef unsigned short u16;
typedef __attribute__((ext_vector_type(8))) short short8;
typedef __attribute__((ext_vector_type(16))) float f32x16;

#define TT 128
#define BB 128
#define II 128
#define HH 512
#define WW 16

__device__ __forceinline__ u16 f2bf(float f) {
  union { float f; uint32_t u; } v; v.f = f;
  uint32_t lsb = (v.u >> 16) & 1u;
  v.u += 0x7fffu + lsb;
  return (u16)(v.u >> 16);
}

struct Params {
  const u16* xb;     // [T][B][I] bf16
  const u16* W1t;    // [2560][512] bf16 : n<512 -> Wv^T col n ; else Wva^T
  const u16* W2t;    // [2560][640] bf16 : n<512 -> [Wq_h|Wq_x] col n ; else [Wh|Wi]
  const float* biba; // [2048] bi+ba
  const float* bvWa; // [2048] bv@Wa
  const float* bv;   // [512]
  const float* bq;   // [512]
  float* Vc;         // [16][128][512]
  float* VAc;        // [16][128][2048]
  float* Q32;        // [128][512]
  float* Ph;         // [128][2048]
  u16* cb;           // [128][512] bf16 c state
  u16* hb;           // [128][512] bf16 h state
  float* c32;        // [128][512] fp32 c state
  float* out;        // [T][B][512] fp32
};

// ---------------- persistent cooperative kernel ----------------
// grid = 160 blocks x 256 threads.
// Phase EA (all blocks): wave-per-32x32-tile GEMMs straight from global (L1/L2 resident):
//   blocks [0,80):  G1: [V|VA]_slot = c @ [Wv|Wva]          (K=512, N=2560)
//   blocks [80,160):G2: [Q|Ph]      = [h|x_t] @ [Wqh,Wqx|Wh,Wi] (K=640, N=2560)
// Phase B (blocks [0,128)): per-batch-row attention + gates, row-local.
__global__ __launch_bounds__(256) void larnn_main(Params p) {
  cg::grid_group grid = cg::this_grid();
  const int tid = threadIdx.x;
  const int lane = tid & 63;
  const int wid = tid >> 6;
  const int blk = blockIdx.x;
  const int lane31 = lane & 31;
  const int lhalf = lane >> 5;

  __shared__ float pre[2048];
  __shared__ float sc[256];
  __shared__ float pw[16];

  const bool isG1 = blk < 80;
  const int n0 = (isG1 ? blk : blk - 80) * 32;
  const int m0 = wid * 32;
  const int gc = n0 + lane31;

  for (int t = 0; t < TT; ++t) {
    // -------- Phase EA --------
    {
      f32x16 acc;
      #pragma unroll
      for (int e = 0; e < 16; ++e) acc[e] = 0.f;
      if (isG1) {
        const u16* Ar = p.cb + (size_t)(m0 + lane31) * HH + lhalf * 8;
        const u16* Br = p.W1t + (size_t)gc * HH + lhalf * 8;
        #pragma unroll 4
        for (int kc = 0; kc < 32; ++kc) {
          short8 a = *(const short8*)(Ar + kc * 16);
          short8 b = *(const short8*)(Br + kc * 16);
          acc = __builtin_amdgcn_mfma_f32_32x32x16_bf16(a, b, acc, 0, 0, 0);
        }
      } else {
        const u16* Ar = p.hb + (size_t)(m0 + lane31) * HH + lhalf * 8;
        const u16* Br = p.W2t + (size_t)gc * 640 + lhalf * 8;
        #pragma unroll 4
        for (int kc = 0; kc < 32; ++kc) {
          short8 a = *(const short8*)(Ar + kc * 16);
          short8 b = *(const short8*)(Br + kc * 16);
          acc = __builtin_amdgcn_mfma_f32_32x32x16_bf16(a, b, acc, 0, 0, 0);
        }
        const u16* Ar2 = p.xb + (size_t)t * BB * II + (size_t)(m0 + lane31) * II + lhalf * 8;
        const u16* Br2 = Br + 512;
        #pragma unroll
        for (int kc = 0; kc < 8; ++kc) {
          short8 a = *(const short8*)(Ar2 + kc * 16);
          short8 b = *(const short8*)(Br2 + kc * 16);
          acc = __builtin_amdgcn_mfma_f32_32x32x16_bf16(a, b, acc, 0, 0, 0);
        }
      }
      // epilogue: acc reg r -> row (r&3) + 8*(r>>2) + 4*(lane>>5), col = lane&31
      const int slot = t & 15;
      if (isG1) {
        if (n0 < HH) {
          const float bias = p.bv[gc];
          float* dst = p.Vc + (size_t)slot * BB * HH + gc;
          #pragma unroll
          for (int r = 0; r < 16; ++r) {
            const int gr = m0 + (r & 3) + ((r >> 2) << 3) + (lhalf << 2);
            dst[(size_t)gr * HH] = acc[r] + bias;
          }
        } else {
          const int j = gc - HH;
          const float bias = p.bvWa[j];
          float* dst = p.VAc + (size_t)slot * BB * 2048 + j;
          #pragma unroll
          for (int r = 0; r < 16; ++r) {
            const int gr = m0 + (r & 3) + ((r >> 2) << 3) + (lhalf << 2);
            dst[(size_t)gr * 2048] = acc[r] + bias;
          }
        }
      } else {
        if (n0 < HH) {
          const float bias = p.bq[gc];
          #pragma unroll
          for (int r = 0; r < 16; ++r) {
            const int gr = m0 + (r & 3) + ((r >> 2) << 3) + (lhalf << 2);
            p.Q32[(size_t)gr * HH + gc] = acc[r] + bias;
          }
        } else {
          const int j = gc - HH;
          const float bias = p.biba[j];
          #pragma unroll
          for (int r = 0; r < 16; ++r) {
            const int gr = m0 + (r & 3) + ((r >> 2) << 3) + (lhalf << 2);
            p.Ph[(size_t)gr * 2048 + j] = acc[r] + bias;
          }
        }
      }
    }
    grid.sync();
    // -------- Phase B (row-local attention + gates) --------
    if (blk < BB) {
      const int b = blk;
      const int nv = (t + 1 < WW) ? (t + 1) : WW;
      {
        const int w = tid >> 4, seg = tid & 15;
        float part = 0.f;
        if (w < nv) {
          const float* vrow = p.Vc + ((size_t)w * BB + b) * HH + seg * 32;
          const float* qrow = p.Q32 + (size_t)b * HH + seg * 32;
          #pragma unroll
          for (int i = 0; i < 32; ++i) part = fmaf(qrow[i], vrow[i], part);
        }
        sc[tid] = part;
      }
      __syncthreads();
      if (tid < 16) {
        float s = 0.f;
        #pragma unroll
        for (int e = 0; e < 16; ++e) s += sc[tid * 16 + e];
        s *= 0.044194173824159216f;  // 1/sqrt(512)
        const float sv = (tid < nv) ? s : -1e30f;
        float m = sv;
        #pragma unroll
        for (int off = 8; off; off >>= 1) m = fmaxf(m, __shfl_xor(m, off, 16));
        const float e = (tid < nv) ? __expf(sv - m) : 0.f;
        float den = e;
        #pragma unroll
        for (int off = 8; off; off >>= 1) den += __shfl_xor(den, off, 16);
        pw[tid] = e / den;
      }
      __syncthreads();
      {
        const int j0 = tid * 8;
        float a0[8];
        const float* ph = p.Ph + (size_t)b * 2048 + j0;
        #pragma unroll
        for (int e = 0; e < 8; ++e) a0[e] = ph[e];
        for (int w = 0; w < nv; ++w) {
          const float pv = pw[w];
          const float* va = p.VAc + ((size_t)w * BB + b) * 2048 + j0;
          #pragma unroll
          for (int e = 0; e < 8; ++e) a0[e] = fmaf(pv, va[e], a0[e]);
        }
        #pragma unroll
        for (int e = 0; e < 8; ++e) pre[j0 + e] = a0[e];
      }
      __syncthreads();
      {
        #pragma unroll
        for (int jj = 0; jj < 2; ++jj) {
          const int j = tid + jj * 256;
          const float xi = pre[j], xf = pre[j + 512], xo = pre[j + 1024], xg = pre[j + 1536];
          const float ig = 1.f / (1.f + __expf(-xi));
          const float fg = 1.f / (1.f + __expf(-xf));
          const float og = 1.f / (1.f + __expf(-xo));
          const float e2 = __expf(2.f * xg);
          const float gg = 1.f - 2.f / (e2 + 1.f);
          const float c = p.c32[(size_t)b * HH + j];
          const float cn = c * fg + ig * gg;
          const float e2c = __expf(2.f * cn);
          const float tc = 1.f - 2.f / (e2c + 1.f);
          const float hn = og * tc;
          p.c32[(size_t)b * HH + j] = cn;
          p.cb[(size_t)b * HH + j] = f2bf(cn);
          p.hb[(size_t)b * HH + j] = f2bf(hn);
          p.out[((size_t)t * BB + b) * HH + j] = hn;
        }
      }
    }
    grid.sync();
  }
}

// ---------------- precompute kernels ----------------
__global__ void k_convert_x(const float* __restrict__ x, u16* __restrict__ xb) {
  const int i = blockIdx.x * 256 + threadIdx.x;  // 524288 threads, 4 elems each
  const float4 v = ((const float4*)x)[i];
  const uint32_t lo = (uint32_t)f2bf(v.x) | ((uint32_t)f2bf(v.y) << 16);
  const uint32_t hi = (uint32_t)f2bf(v.z) | ((uint32_t)f2bf(v.w) << 16);
  ((uint2*)xb)[i] = make_uint2(lo, hi);
}

__global__ void k_pack_w2t(const float* __restrict__ Wq, const float* __restrict__ Wh,
                           const float* __restrict__ Wi, u16* __restrict__ W2t) {
  const int id = blockIdx.x * 256 + threadIdx.x;  // 640*2560
  const int n = id % 2560, k = id / 2560;
  float v;
  if (n < 512) v = (k < 512) ? Wq[(size_t)(128 + k) * 512 + n] : Wq[(size_t)(k - 512) * 512 + n];
  else         v = (k < 512) ? Wh[(size_t)k * 2048 + (n - 512)] : Wi[(size_t)(k - 512) * 2048 + (n - 512)];
  W2t[(size_t)n * 640 + k] = f2bf(v);
}

__global__ void k_pack_w1v(const float* __restrict__ Wv, u16* __restrict__ W1t) {
  const int id = blockIdx.x * 256 + threadIdx.x;  // 512*512
  const int n = id & 511, k = id >> 9;
  W1t[(size_t)n * 512 + k] = f2bf(Wv[(size_t)k * 512 + n]);
}

// Wva[k][j] = sum_m Wv[k][m]*Wa[m][j]; store transposed into W1t rows 512..2559 (bf16)
__global__ void k_wva(const float* __restrict__ Wv, const float* __restrict__ Wa,
                      u16* __restrict__ W1t) {
  __shared__ float As[64][33];
  __shared__ float Bs[32][65];
  const int tx = threadIdx.x & 15, ty = threadIdx.x >> 4;
  const int j0 = blockIdx.x * 64, k0 = blockIdx.y * 64;
  float acc[4][4] = {};
  for (int m0 = 0; m0 < 512; m0 += 32) {
    __syncthreads();
    #pragma unroll
    for (int it = 0; it < 8; ++it) {
      const int id = threadIdx.x + it * 256;
      As[id >> 5][id & 31] = Wv[(size_t)(k0 + (id >> 5)) * 512 + m0 + (id & 31)];
    }
    #pragma unroll
    for (int it = 0; it < 8; ++it) {
      const int id = threadIdx.x + it * 256;
      Bs[id >> 6][id & 63] = Wa[(size_t)(m0 + (id >> 6)) * 2048 + j0 + (id & 63)];
    }
    __syncthreads();
    #pragma unroll
    for (int mm = 0; mm < 32; ++mm) {
      float a[4], b[4];
      #pragma unroll
      for (int e = 0; e < 4; ++e) a[e] = As[ty * 4 + e][mm];
      #pragma unroll
      for (int e = 0; e < 4; ++e) b[e] = Bs[mm][tx * 4 + e];
      #pragma unroll
      for (int r = 0; r < 4; ++r)
        #pragma unroll
        for (int c = 0; c < 4; ++c) acc[r][c] = fmaf(a[r], b[c], acc[r][c]);
    }
  }
  #pragma unroll
  for (int r = 0; r < 4; ++r)
    #pragma unroll
    for (int c = 0; c < 4; ++c) {
      const int k = k0 + ty * 4 + r, j = j0 + tx * 4 + c;
      W1t[(size_t)(512 + j) * 512 + k] = f2bf(acc[r][c]);
    }
}

__global__ void k_bias(const float* __restrict__ bv, const float* __restrict__ Wa,
                       const float* __restrict__ bi, const float* __restrict__ ba,
                       float* __restrict__ bvWa, float* __restrict__ biba) {
  const int j = blockIdx.x * 256 + threadIdx.x;  // 2048
  float s = 0.f;
  for (int k = 0; k < 512; ++k) s = fmaf(bv[k], Wa[(size_t)k * 2048 + j], s);
  bvWa[j] = s;
  biba[j] = bi[j] + ba[j];
}

extern "C" void kernel_launch(void* const* d_in, const int* in_sizes, int n_in,
                              void* d_out, int out_size, void* d_ws, size_t ws_size,
                              hipStream_t stream) {
  const float* x  = (const float*)d_in[0];
  const float* Wi = (const float*)d_in[1];
  const float* bi = (const float*)d_in[2];
  const float* Wh = (const float*)d_in[3];
  const float* Wv = (const float*)d_in[4];
  const float* bv = (const float*)d_in[5];
  const float* Wq = (const float*)d_in[6];
  const float* bq = (const float*)d_in[7];
  const float* Wa = (const float*)d_in[8];
  const float* ba = (const float*)d_in[9];
  float* out = (float*)d_out;

  char* w = (char*)d_ws;
  size_t off = 0;
  auto alloc = [&](size_t bytes) -> void* {
    void* pp = w + off;
    off += (bytes + 255) & ~(size_t)255;
    return pp;
  };
  u16* xb    = (u16*)alloc((size_t)TT * BB * II * 2);        // 4 MB
  u16* W1t   = (u16*)alloc((size_t)2560 * 512 * 2);          // 2.5 MB
  u16* W2t   = (u16*)alloc((size_t)2560 * 640 * 2);          // 3.1 MB
  float* Vc  = (float*)alloc((size_t)16 * BB * HH * 4);      // 4 MB
  float* VAc = (float*)alloc((size_t)16 * BB * 2048 * 4);    // 16 MB
  float* Q32 = (float*)alloc((size_t)BB * HH * 4);
  float* Ph  = (float*)alloc((size_t)BB * 2048 * 4);
  float* biba = (float*)alloc(2048 * 4);
  float* bvWa = (float*)alloc(2048 * 4);
  u16* cb    = (u16*)alloc((size_t)BB * HH * 2);
  u16* hb    = (u16*)alloc((size_t)BB * HH * 2);
  float* c32 = (float*)alloc((size_t)BB * HH * 4);
  (void)ws_size; (void)in_sizes; (void)n_in; (void)out_size;

  // zero the recurrent state (cb, hb, c32 are contiguous, 256B-aligned blocks)
  hipMemsetAsync(cb, 0, (size_t)BB * HH * 2 * 2 + (size_t)BB * HH * 4, stream);

  k_convert_x<<<2048, 256, 0, stream>>>(x, xb);
  k_pack_w2t<<<6400, 256, 0, stream>>>(Wq, Wh, Wi, W2t);
  k_pack_w1v<<<1024, 256, 0, stream>>>(Wv, W1t);
  k_wva<<<dim3(32, 8), 256, 0, stream>>>(Wv, Wa, W1t);
  k_bias<<<8, 256, 0, stream>>>(bv, Wa, bi, ba, bvWa, biba);

  Params prm;
  prm.xb = xb; prm.W1t = W1t; prm.W2t = W2t;
  prm.biba = biba; prm.bvWa = bvWa; prm.bv = bv; prm.bq = bq;
  prm.Vc = Vc; prm.VAc = VAc; prm.Q32 = Q32; prm.Ph = Ph;
  prm.cb = cb; prm.hb = hb; prm.c32 = c32; prm.out = out;
  void* args[] = {&prm};
  hipLaunchCooperativeKernel(reinterpret_cast<void*>(larnn_main), dim3(160), dim3(256),
                             args, 0, stream);
}

// Round 2
// 4084.109 us; speedup vs baseline: 1.7917x; 1.7917x over previous
//
#include <hip/hip_runtime.h>
#include <hip/hip_bf16.h>
#include <cstdint>
#include <cstddef>

typedef unsigned short u16;
typedef __attribute__((ext_vector_type(8))) short short8;
typedef __attribute__((ext_vector_type(16))) float f32x16;

#define TT 128
#define BB 128
#define II 128
#define HH 512
#define WW 16
#define NBLK 160

__device__ __forceinline__ u16 f2bf(float f) {
  union { float f; uint32_t u; } v; v.f = f;
  uint32_t lsb = (v.u >> 16) & 1u;
  v.u += 0x7fffu + lsb;
  return (u16)(v.u >> 16);
}

struct Params {
  const u16* xb;     // [T][B][I] bf16
  const u16* W1t;    // [2560][512] bf16 : n<512 -> Wv^T col n ; else Wva^T
  const u16* W2t;    // [2560][640] bf16 : n<512 -> [Wq_h|Wq_x] col n ; else [Wh|Wi]
  const float* biba; // [2048] bi+ba
  const float* bvWa; // [2048] bv@Wa
  const float* bv;   // [512]
  const float* bq;   // [512]
  float* Vc;         // [16][128][512]
  float* VAc;        // [16][128][2048]
  float* Q32;        // [128][512]
  float* Ph;         // [128][2048]
  u16* cb;           // [128][512] bf16 c state
  u16* hb;           // [128][512] bf16 h state
  float* c32;        // [128][512] fp32 c state
  float* out;        // [T][B][512] fp32
  uint32_t* barc;    // barrier counters: [0..127] group cnts (stride 16), [128] root
};

// Two-level grid barrier. Groups of 20 blocks arrive on one of 8 padded
// counters; last arrival of each group bumps the root; everyone spins on root.
// Data correctness: CDNA L1 is write-through, so after __syncthreads all block
// stores are in L2; the ACQ_REL agent-scope RMW writes back this XCD's dirty
// L2 (release) so data is in LLC before the increment is visible; the ACQUIRE
// fence after the spin invalidates L1/L2 so post-barrier loads refetch.
__device__ __forceinline__ void gbar(uint32_t* barc, int grp, uint32_t rnd) {
  __syncthreads();
  if (threadIdx.x == 0) {
    uint32_t old = __hip_atomic_fetch_add(&barc[grp * 16], 1u,
                                          __ATOMIC_ACQ_REL, __HIP_MEMORY_SCOPE_AGENT);
    if (old == rnd * 20u + 19u)
      __hip_atomic_fetch_add(&barc[128], 1u,
                             __ATOMIC_RELEASE, __HIP_MEMORY_SCOPE_AGENT);
    while (__hip_atomic_load(&barc[128], __ATOMIC_RELAXED,
                             __HIP_MEMORY_SCOPE_AGENT) < rnd * 8u + 8u) {}
    __builtin_amdgcn_fence(__ATOMIC_ACQUIRE, "agent");
  }
  __syncthreads();
}

// ---------------- persistent cooperative kernel ----------------
// grid = 160 blocks x 256 threads.
// Phase EA (all blocks): wave-per-32x32-tile GEMMs straight from global:
//   blocks [0,80):  G1: [V|VA]_slot = c @ [Wv|Wva]          (K=512, N=2560)
//   blocks [80,160):G2: [Q|Ph]      = [h|x_t] @ [Wqh,Wqx|Wh,Wi] (K=640, N=2560)
// Phase B (blocks [0,128)): per-batch-row attention + gates, row-local.
__global__ __launch_bounds__(256) void larnn_main(Params p) {
  const int tid = threadIdx.x;
  const int lane = tid & 63;
  const int wid = tid >> 6;
  const int blk = blockIdx.x;
  const int lane31 = lane & 31;
  const int lhalf = lane >> 5;
  const int grp = blk & 7;

  __shared__ float pre[2048];
  __shared__ float sc[256];
  __shared__ float pw[16];

  const bool isG1 = blk < 80;
  const int n0 = (isG1 ? blk : blk - 80) * 32;
  const int m0 = wid * 32;
  const int gc = n0 + lane31;

  uint32_t rnd = 0;

  for (int t = 0; t < TT; ++t) {
    // -------- Phase EA --------
    {
      f32x16 acc0, acc1;
      #pragma unroll
      for (int e = 0; e < 16; ++e) { acc0[e] = 0.f; acc1[e] = 0.f; }
      if (isG1) {
        const u16* Ar = p.cb + (size_t)(m0 + lane31) * HH + lhalf * 8;
        const u16* Br = p.W1t + (size_t)gc * HH + lhalf * 8;
        #pragma unroll 4
        for (int kc = 0; kc < 16; ++kc) {
          short8 a0 = *(const short8*)(Ar + kc * 32);
          short8 b0 = *(const short8*)(Br + kc * 32);
          short8 a1 = *(const short8*)(Ar + kc * 32 + 16);
          short8 b1 = *(const short8*)(Br + kc * 32 + 16);
          acc0 = __builtin_amdgcn_mfma_f32_32x32x16_bf16(a0, b0, acc0, 0, 0, 0);
          acc1 = __builtin_amdgcn_mfma_f32_32x32x16_bf16(a1, b1, acc1, 0, 0, 0);
        }
      } else {
        const u16* Ar = p.hb + (size_t)(m0 + lane31) * HH + lhalf * 8;
        const u16* Br = p.W2t + (size_t)gc * 640 + lhalf * 8;
        #pragma unroll 4
        for (int kc = 0; kc < 16; ++kc) {
          short8 a0 = *(const short8*)(Ar + kc * 32);
          short8 b0 = *(const short8*)(Br + kc * 32);
          short8 a1 = *(const short8*)(Ar + kc * 32 + 16);
          short8 b1 = *(const short8*)(Br + kc * 32 + 16);
          acc0 = __builtin_amdgcn_mfma_f32_32x32x16_bf16(a0, b0, acc0, 0, 0, 0);
          acc1 = __builtin_amdgcn_mfma_f32_32x32x16_bf16(a1, b1, acc1, 0, 0, 0);
        }
        const u16* Ar2 = p.xb + (size_t)t * BB * II + (size_t)(m0 + lane31) * II + lhalf * 8;
        const u16* Br2 = Br + 512;
        #pragma unroll
        for (int kc = 0; kc < 4; ++kc) {
          short8 a0 = *(const short8*)(Ar2 + kc * 32);
          short8 b0 = *(const short8*)(Br2 + kc * 32);
          short8 a1 = *(const short8*)(Ar2 + kc * 32 + 16);
          short8 b1 = *(const short8*)(Br2 + kc * 32 + 16);
          acc0 = __builtin_amdgcn_mfma_f32_32x32x16_bf16(a0, b0, acc0, 0, 0, 0);
          acc1 = __builtin_amdgcn_mfma_f32_32x32x16_bf16(a1, b1, acc1, 0, 0, 0);
        }
      }
      f32x16 acc = acc0 + acc1;
      // epilogue: acc reg r -> row (r&3) + 8*(r>>2) + 4*(lane>>5), col = lane&31
      const int slot = t & 15;
      if (isG1) {
        if (n0 < HH) {
          const float bias = p.bv[gc];
          float* dst = p.Vc + (size_t)slot * BB * HH + gc;
          #pragma unroll
          for (int r = 0; r < 16; ++r) {
            const int gr = m0 + (r & 3) + ((r >> 2) << 3) + (lhalf << 2);
            dst[(size_t)gr * HH] = acc[r] + bias;
          }
        } else {
          const int j = gc - HH;
          const float bias = p.bvWa[j];
          float* dst = p.VAc + (size_t)slot * BB * 2048 + j;
          #pragma unroll
          for (int r = 0; r < 16; ++r) {
            const int gr = m0 + (r & 3) + ((r >> 2) << 3) + (lhalf << 2);
            dst[(size_t)gr * 2048] = acc[r] + bias;
          }
        }
      } else {
        if (n0 < HH) {
          const float bias = p.bq[gc];
          #pragma unroll
          for (int r = 0; r < 16; ++r) {
            const int gr = m0 + (r & 3) + ((r >> 2) << 3) + (lhalf << 2);
            p.Q32[(size_t)gr * HH + gc] = acc[r] + bias;
          }
        } else {
          const int j = gc - HH;
          const float bias = p.biba[j];
          #pragma unroll
          for (int r = 0; r < 16; ++r) {
            const int gr = m0 + (r & 3) + ((r >> 2) << 3) + (lhalf << 2);
            p.Ph[(size_t)gr * 2048 + j] = acc[r] + bias;
          }
        }
      }
    }
    gbar(p.barc, grp, rnd); ++rnd;
    // -------- Phase B (row-local attention + gates) --------
    if (blk < BB) {
      const int b = blk;
      const int nv = (t + 1 < WW) ? (t + 1) : WW;
      {
        const int w = tid >> 4, seg = tid & 15;
        float part = 0.f;
        if (w < nv) {
          const float* vrow = p.Vc + ((size_t)w * BB + b) * HH + seg * 32;
          const float* qrow = p.Q32 + (size_t)b * HH + seg * 32;
          #pragma unroll
          for (int i = 0; i < 32; ++i) part = fmaf(qrow[i], vrow[i], part);
        }
        sc[tid] = part;
      }
      __syncthreads();
      if (tid < 16) {
        float s = 0.f;
        #pragma unroll
        for (int e = 0; e < 16; ++e) s += sc[tid * 16 + e];
        s *= 0.044194173824159216f;  // 1/sqrt(512)
        const float sv = (tid < nv) ? s : -1e30f;
        float m = sv;
        #pragma unroll
        for (int off = 8; off; off >>= 1) m = fmaxf(m, __shfl_xor(m, off, 16));
        const float e = (tid < nv) ? __expf(sv - m) : 0.f;
        float den = e;
        #pragma unroll
        for (int off = 8; off; off >>= 1) den += __shfl_xor(den, off, 16);
        pw[tid] = e / den;
      }
      __syncthreads();
      {
        const int j0 = tid * 8;
        float a0[8];
        const float* ph = p.Ph + (size_t)b * 2048 + j0;
        #pragma unroll
        for (int e = 0; e < 8; ++e) a0[e] = ph[e];
        for (int w = 0; w < nv; ++w) {
          const float pv = pw[w];
          const float* va = p.VAc + ((size_t)w * BB + b) * 2048 + j0;
          #pragma unroll
          for (int e = 0; e < 8; ++e) a0[e] = fmaf(pv, va[e], a0[e]);
        }
        #pragma unroll
        for (int e = 0; e < 8; ++e) pre[j0 + e] = a0[e];
      }
      __syncthreads();
      {
        #pragma unroll
        for (int jj = 0; jj < 2; ++jj) {
          const int j = tid + jj * 256;
          const float xi = pre[j], xf = pre[j + 512], xo = pre[j + 1024], xg = pre[j + 1536];
          const float ig = 1.f / (1.f + __expf(-xi));
          const float fg = 1.f / (1.f + __expf(-xf));
          const float og = 1.f / (1.f + __expf(-xo));
          const float e2 = __expf(2.f * xg);
          const float gg = 1.f - 2.f / (e2 + 1.f);
          const float c = p.c32[(size_t)b * HH + j];
          const float cn = c * fg + ig * gg;
          const float e2c = __expf(2.f * cn);
          const float tc = 1.f - 2.f / (e2c + 1.f);
          const float hn = og * tc;
          p.c32[(size_t)b * HH + j] = cn;
          p.cb[(size_t)b * HH + j] = f2bf(cn);
          p.hb[(size_t)b * HH + j] = f2bf(hn);
          p.out[((size_t)t * BB + b) * HH + j] = hn;
        }
      }
    }
    gbar(p.barc, grp, rnd); ++rnd;
  }
}

// ---------------- precompute kernels ----------------
__global__ void k_convert_x(const float* __restrict__ x, u16* __restrict__ xb) {
  const int i = blockIdx.x * 256 + threadIdx.x;  // 524288 threads, 4 elems each
  const float4 v = ((const float4*)x)[i];
  const uint32_t lo = (uint32_t)f2bf(v.x) | ((uint32_t)f2bf(v.y) << 16);
  const uint32_t hi = (uint32_t)f2bf(v.z) | ((uint32_t)f2bf(v.w) << 16);
  ((uint2*)xb)[i] = make_uint2(lo, hi);
}

__global__ void k_pack_w2t(const float* __restrict__ Wq, const float* __restrict__ Wh,
                           const float* __restrict__ Wi, u16* __restrict__ W2t) {
  const int id = blockIdx.x * 256 + threadIdx.x;  // 640*2560
  const int n = id % 2560, k = id / 2560;
  float v;
  if (n < 512) v = (k < 512) ? Wq[(size_t)(128 + k) * 512 + n] : Wq[(size_t)(k - 512) * 512 + n];
  else         v = (k < 512) ? Wh[(size_t)k * 2048 + (n - 512)] : Wi[(size_t)(k - 512) * 2048 + (n - 512)];
  W2t[(size_t)n * 640 + k] = f2bf(v);
}

__global__ void k_pack_w1v(const float* __restrict__ Wv, u16* __restrict__ W1t) {
  const int id = blockIdx.x * 256 + threadIdx.x;  // 512*512
  const int n = id & 511, k = id >> 9;
  W1t[(size_t)n * 512 + k] = f2bf(Wv[(size_t)k * 512 + n]);
}

// Wva[k][j] = sum_m Wv[k][m]*Wa[m][j]; store transposed into W1t rows 512..2559 (bf16)
__global__ void k_wva(const float* __restrict__ Wv, const float* __restrict__ Wa,
                      u16* __restrict__ W1t) {
  __shared__ float As[64][33];
  __shared__ float Bs[32][65];
  const int tx = threadIdx.x & 15, ty = threadIdx.x >> 4;
  const int j0 = blockIdx.x * 64, k0 = blockIdx.y * 64;
  float acc[4][4] = {};
  for (int m0 = 0; m0 < 512; m0 += 32) {
    __syncthreads();
    #pragma unroll
    for (int it = 0; it < 8; ++it) {
      const int id = threadIdx.x + it * 256;
      As[id >> 5][id & 31] = Wv[(size_t)(k0 + (id >> 5)) * 512 + m0 + (id & 31)];
    }
    #pragma unroll
    for (int it = 0; it < 8; ++it) {
      const int id = threadIdx.x + it * 256;
      Bs[id >> 6][id & 63] = Wa[(size_t)(m0 + (id >> 6)) * 2048 + j0 + (id & 63)];
    }
    __syncthreads();
    #pragma unroll
    for (int mm = 0; mm < 32; ++mm) {
      float a[4], b[4];
      #pragma unroll
      for (int e = 0; e < 4; ++e) a[e] = As[ty * 4 + e][mm];
      #pragma unroll
      for (int e = 0; e < 4; ++e) b[e] = Bs[mm][tx * 4 + e];
      #pragma unroll
      for (int r = 0; r < 4; ++r)
        #pragma unroll
        for (int c = 0; c < 4; ++c) acc[r][c] = fmaf(a[r], b[c], acc[r][c]);
    }
  }
  #pragma unroll
  for (int r = 0; r < 4; ++r)
    #pragma unroll
    for (int c = 0; c < 4; ++c) {
      const int k = k0 + ty * 4 + r, j = j0 + tx * 4 + c;
      W1t[(size_t)(512 + j) * 512 + k] = f2bf(acc[r][c]);
    }
}

__global__ void k_bias(const float* __restrict__ bv, const float* __restrict__ Wa,
                       const float* __restrict__ bi, const float* __restrict__ ba,
                       float* __restrict__ bvWa, float* __restrict__ biba) {
  const int j = blockIdx.x * 256 + threadIdx.x;  // 2048
  float s = 0.f;
  for (int k = 0; k < 512; ++k) s = fmaf(bv[k], Wa[(size_t)k * 2048 + j], s);
  bvWa[j] = s;
  biba[j] = bi[j] + ba[j];
}

extern "C" void kernel_launch(void* const* d_in, const int* in_sizes, int n_in,
                              void* d_out, int out_size, void* d_ws, size_t ws_size,
                              hipStream_t stream) {
  const float* x  = (const float*)d_in[0];
  const float* Wi = (const float*)d_in[1];
  const float* bi = (const float*)d_in[2];
  const float* Wh = (const float*)d_in[3];
  const float* Wv = (const float*)d_in[4];
  const float* bv = (const float*)d_in[5];
  const float* Wq = (const float*)d_in[6];
  const float* bq = (const float*)d_in[7];
  const float* Wa = (const float*)d_in[8];
  const float* ba = (const float*)d_in[9];
  float* out = (float*)d_out;

  char* w = (char*)d_ws;
  size_t off = 0;
  auto alloc = [&](size_t bytes) -> void* {
    void* pp = w + off;
    off += (bytes + 255) & ~(size_t)255;
    return pp;
  };
  u16* xb    = (u16*)alloc((size_t)TT * BB * II * 2);        // 4 MB
  u16* W1t   = (u16*)alloc((size_t)2560 * 512 * 2);          // 2.5 MB
  u16* W2t   = (u16*)alloc((size_t)2560 * 640 * 2);          // 3.1 MB
  float* Vc  = (float*)alloc((size_t)16 * BB * HH * 4);      // 4 MB
  float* VAc = (float*)alloc((size_t)16 * BB * 2048 * 4);    // 16 MB
  float* Q32 = (float*)alloc((size_t)BB * HH * 4);
  float* Ph  = (float*)alloc((size_t)BB * 2048 * 4);
  float* biba = (float*)alloc(2048 * 4);
  float* bvWa = (float*)alloc(2048 * 4);
  u16* cb    = (u16*)alloc((size_t)BB * HH * 2);
  u16* hb    = (u16*)alloc((size_t)BB * HH * 2);
  float* c32 = (float*)alloc((size_t)BB * HH * 4);
  uint32_t* barc = (uint32_t*)alloc(4096);
  (void)ws_size; (void)in_sizes; (void)n_in; (void)out_size;

  // zero the recurrent state (cb, hb, c32 are contiguous, 256B-aligned blocks)
  hipMemsetAsync(cb, 0, (size_t)BB * HH * 2 * 2 + (size_t)BB * HH * 4, stream);
  hipMemsetAsync(barc, 0, 4096, stream);

  k_convert_x<<<2048, 256, 0, stream>>>(x, xb);
  k_pack_w2t<<<6400, 256, 0, stream>>>(Wq, Wh, Wi, W2t);
  k_pack_w1v<<<1024, 256, 0, stream>>>(Wv, W1t);
  k_wva<<<dim3(32, 8), 256, 0, stream>>>(Wv, Wa, W1t);
  k_bias<<<8, 256, 0, stream>>>(bv, Wa, bi, ba, bvWa, biba);

  Params prm;
  prm.xb = xb; prm.W1t = W1t; prm.W2t = W2t;
  prm.biba = biba; prm.bvWa = bvWa; prm.bv = bv; prm.bq = bq;
  prm.Vc = Vc; prm.VAc = VAc; prm.Q32 = Q32; prm.Ph = Ph;
  prm.cb = cb; prm.hb = hb; prm.c32 = c32; prm.out = out;
  prm.barc = barc;
  void* args[] = {&prm};
  hipLaunchCooperativeKernel(reinterpret_cast<void*>(larnn_main), dim3(NBLK), dim3(256),
                             args, 0, stream);
}